// Round 2
// baseline (51004.532 us; speedup 1.0000x reference)
//
#include <hip/hip_runtime.h>
#include <cstdint>
#include <cstddef>

// ---------------- problem constants ----------------
#define B_   32
#define S_   1024
#define IN_  128
#define H_   512
#define OUT_ 128
#define NL_  3
#define NWG_LAYER 96            // 3 layers x 32 n-tiles
#define NWG_TOT   104           // + 8 output-projection WGs
#define NSTEP (S_ + NL_)        // 1027 pipeline steps

typedef __attribute__((ext_vector_type(8))) short short8;   // 8 bf16 (4 VGPRs)
typedef __attribute__((ext_vector_type(4))) float floatx4;  // MFMA C/D

// ---------------- workspace layout (bytes); total ~12.6 MB ----------------
constexpr size_t OFF_BAR  = 0;                        // 2 uints (counter, gen)
constexpr size_t OFF_W0Z  = 256;                      // 512x128 bf16
constexpr size_t OFF_W0R  = OFF_W0Z + 131072;
constexpr size_t OFF_W0G  = OFF_W0R + 131072;
constexpr size_t OFF_WXZ  = OFF_W0G + 131072;         // 512x512 bf16 each
constexpr size_t OFF_WXR  = OFF_WXZ + 524288;
constexpr size_t OFF_WXG  = OFF_WXR + 524288;
constexpr size_t OFF_WHZ  = OFF_WXG + 524288;
constexpr size_t OFF_WHR  = OFF_WHZ + 524288;
constexpr size_t OFF_WHG  = OFF_WHR + 524288;
constexpr size_t OFF_WOUT = OFF_WHG + 524288;         // 128x512 bf16
constexpr size_t OFF_XBF  = OFF_WOUT + 131072;        // x bf16 [32][1024][128]
constexpr size_t OFF_HST  = OFF_XBF + 8388608;        // f32 h state [3][32][512]
constexpr size_t OFF_HBF  = OFF_HST + 196608;         // bf16 h double-buf [3][2][32][512]
constexpr size_t OFF_RH   = OFF_HBF + 196608;         // bf16 r*h [3][32][512]
// end = OFF_RH + 98304 = 12,550,400 bytes

__device__ __forceinline__ unsigned short f2bf(float f) {
    unsigned u = __float_as_uint(f);
    unsigned r = (u + 0x7FFFu + ((u >> 16) & 1u)) >> 16;
    return (unsigned short)r;
}
__device__ __forceinline__ float sigmoidf_(float x) { return 1.0f / (1.0f + __expf(-x)); }

// ---------------- pre-pass: converts + init ----------------
__global__ void __launch_bounds__(1024) prep_kernel(
    const float* __restrict__ x, const float* __restrict__ h0,
    const float* __restrict__ W0z, const float* __restrict__ W0r, const float* __restrict__ W0g,
    const float* __restrict__ Wxz, const float* __restrict__ Wxr, const float* __restrict__ Wxg,
    const float* __restrict__ Whz, const float* __restrict__ Whr, const float* __restrict__ Whg,
    const float* __restrict__ Wout, char* __restrict__ ws)
{
    int i = blockIdx.x * 1024 + threadIdx.x;
    unsigned short* xbf = (unsigned short*)(ws + OFF_XBF);
    if (i < B_ * S_ * IN_) xbf[i] = f2bf(x[i]);
    if (i < 65536) {
        ((unsigned short*)(ws + OFF_W0Z))[i]  = f2bf(W0z[i]);
        ((unsigned short*)(ws + OFF_W0R))[i]  = f2bf(W0r[i]);
        ((unsigned short*)(ws + OFF_W0G))[i]  = f2bf(W0g[i]);
        ((unsigned short*)(ws + OFF_WOUT))[i] = f2bf(Wout[i]);
    }
    if (i < 262144) {
        ((unsigned short*)(ws + OFF_WXZ))[i] = f2bf(Wxz[i]);
        ((unsigned short*)(ws + OFF_WXR))[i] = f2bf(Wxr[i]);
        ((unsigned short*)(ws + OFF_WXG))[i] = f2bf(Wxg[i]);
        ((unsigned short*)(ws + OFF_WHZ))[i] = f2bf(Whz[i]);
        ((unsigned short*)(ws + OFF_WHR))[i] = f2bf(Whr[i]);
        ((unsigned short*)(ws + OFF_WHG))[i] = f2bf(Whg[i]);
    }
    if (i < B_ * NL_ * H_) {
        int b = i / (NL_ * H_); int r = i % (NL_ * H_); int j = r / H_; int n = r % H_;
        float v = h0[i];
        ((float*)(ws + OFF_HST))[(j * B_ + b) * H_ + n] = v;
        int par = (j + 1) & 1;  // parity read at layer j's first active step (s=j reads (s-1)&1)
        ((unsigned short*)(ws + OFF_HBF))[((j * 2 + par) * B_ + b) * H_ + n] = f2bf(v);
    }
    if (i == 0) { ((unsigned*)(ws + OFF_BAR))[0] = 0u; ((unsigned*)(ws + OFF_BAR))[1] = 0u; }
}

// ---------------- grid barrier (device-scope, sense-reversing, ordered) ----------------
__device__ __forceinline__ void gbar(unsigned* cnt, unsigned* gen) {
    __syncthreads();                 // all waves drained (vmcnt(0) before s_barrier)
    if (threadIdx.x == 0) {
        __threadfence();             // release: L2 writeback so other XCDs see our stores
        unsigned g = __hip_atomic_load(gen, __ATOMIC_RELAXED, __HIP_MEMORY_SCOPE_AGENT);
        unsigned a = __hip_atomic_fetch_add(cnt, 1u, __ATOMIC_ACQ_REL, __HIP_MEMORY_SCOPE_AGENT);
        if (a == (unsigned)(NWG_TOT - 1)) {
            __hip_atomic_store(cnt, 0u, __ATOMIC_RELAXED, __HIP_MEMORY_SCOPE_AGENT);
            // RELEASE orders the cnt reset before the generation bump becomes visible
            __hip_atomic_store(gen, g + 1u, __ATOMIC_RELEASE, __HIP_MEMORY_SCOPE_AGENT);
        } else {
            while (__hip_atomic_load(gen, __ATOMIC_ACQUIRE, __HIP_MEMORY_SCOPE_AGENT) == g)
                __builtin_amdgcn_s_sleep(1);
        }
    }
    __syncthreads();
    __threadfence();                 // acquire for every wave: invalidate stale L1/L2
}

// ---------------- the scan: 104 WGs, layer+output pipelined, weights in registers ----------------
__global__ void __launch_bounds__(256, 1) gru_kernel(char* ws,
    const float* __restrict__ b0z, const float* __restrict__ b0r, const float* __restrict__ b0g,
    const float* __restrict__ bxz, const float* __restrict__ bxr, const float* __restrict__ bxg,
    const float* __restrict__ bout, float* __restrict__ out)
{
    const int wg    = blockIdx.x;          // 0..103
    const bool is_out = (wg >= NWG_LAYER);
    const int v     = threadIdx.x >> 6;    // wave 0..3
    const int lane  = threadIdx.x & 63;
    const int btile = v & 1;
    const int khalf = v >> 1;
    const int l15   = lane & 15;
    const int quad  = lane >> 4;
    const int koff  = quad * 8;
    const int arow  = btile * 16 + l15;    // A row (batch)

    unsigned short* hbf_base = (unsigned short*)(ws + OFF_HBF);
    unsigned* cnt = (unsigned*)(ws + OFF_BAR);
    unsigned* gen = cnt + 1;

    __shared__ float part[4][2][256];

    // ----- layer-WG setup -----
    const int j  = is_out ? 0 : (wg >> 5);     // layer 0..2
    const int nt = wg & 31;                    // n-tile
    const int nrow = nt * 16 + l15;            // feature (layer path)
    const int Tx = (j == 0) ? 4 : 16;          // x-part k-tiles (32 elems each)
    const int T1 = Tx + 16;                    // + h-part
    float bzv = 0.f, brv = 0.f, bgv = 0.f;
    short8 bzc[16], brc[16], bgc[16];
    const short* xbf = (const short*)(ws + OFF_XBF);
    float* hst = (float*)(ws + OFF_HST) + (size_t)j * B_ * H_;
    unsigned short* rh_j = (unsigned short*)(ws + OFF_RH) + (size_t)j * B_ * H_;

    // ----- output-WG setup -----
    const int ont  = wg - NWG_LAYER;           // 0..7
    const int orow = ont * 16 + l15;           // out feature 0..127
    short8 wc[8];
    float bov = 0.f;

    if (!is_out) {
        const float* bz_b = (j == 0) ? b0z : bxz;
        const float* br_b = (j == 0) ? b0r : bxr;
        const float* bg_b = (j == 0) ? b0g : bxg;
        bzv = bz_b[nrow]; brv = br_b[nrow]; bgv = bg_b[nrow];
        const int strx = (j == 0) ? IN_ : H_;
        const short* Wz_x = (const short*)(ws + ((j == 0) ? OFF_W0Z : OFF_WXZ));
        const short* Wr_x = (const short*)(ws + ((j == 0) ? OFF_W0R : OFF_WXR));
        const short* Wg_x = (const short*)(ws + ((j == 0) ? OFF_W0G : OFF_WXG));
        const short* Wz_h = (const short*)(ws + OFF_WHZ);
        const short* Wr_h = (const short*)(ws + OFF_WHR);
        const short* Wg_h = (const short*)(ws + OFF_WHG);
#pragma unroll
        for (int kt = 0; kt < 16; ++kt) {
            short8 z8 = {0, 0, 0, 0, 0, 0, 0, 0};
            bzc[kt] = z8; brc[kt] = z8; bgc[kt] = z8;
            int g = khalf * 16 + kt;
            if (g < T1) {
                if (g < Tx) {
                    long o = (long)nrow * strx + g * 32 + koff;
                    bzc[kt] = *(const short8*)(Wz_x + o);
                    brc[kt] = *(const short8*)(Wr_x + o);
                    bgc[kt] = *(const short8*)(Wg_x + o);
                } else {
                    long o = (long)nrow * H_ + (g - Tx) * 32 + koff;
                    bzc[kt] = *(const short8*)(Wz_h + o);
                    brc[kt] = *(const short8*)(Wr_h + o);
                    bgc[kt] = *(const short8*)(Wg_h + o);
                }
            }
        }
    } else {
        const short* Wo = (const short*)(ws + OFF_WOUT);
        bov = bout[orow];
#pragma unroll
        for (int kt = 0; kt < 8; ++kt) {
            int g = khalf * 8 + kt;   // 16 k-tiles total, split 8/8 across khalf
            wc[kt] = *(const short8*)(Wo + (long)orow * H_ + g * 32 + koff);
        }
    }

    float zreg[4] = {0.f, 0.f, 0.f, 0.f};

#pragma unroll 1
    for (int s = 0; s < NSTEP; ++s) {
        const int rdpar = (s - 1) & 1;

        if (!is_out) {
            // ============ layer phase 1: zlin, rlin ============
            const int t = s - j;
            const bool act = (t >= 0) && (t < S_);
            floatx4 az = {0.f, 0.f, 0.f, 0.f}, ar = {0.f, 0.f, 0.f, 0.f};
            if (act) {
                const short* hbf_rd = (const short*)(hbf_base + ((size_t)(j * 2 + rdpar)) * B_ * H_);
                const short* inp_rd = (j == 0) ? nullptr
                                    : (const short*)(hbf_base + ((size_t)((j - 1) * 2 + rdpar)) * B_ * H_);
#pragma unroll
                for (int kt = 0; kt < 16; ++kt) {
                    int g = khalf * 16 + kt;
                    if (g < T1) {
                        const short* ap;
                        if (g < Tx) {
                            if (j == 0) ap = xbf + (long)arow * (S_ * IN_) + (long)t * IN_ + g * 32 + koff;
                            else        ap = inp_rd + (long)arow * H_ + g * 32 + koff;
                        } else {
                            ap = hbf_rd + (long)arow * H_ + (g - Tx) * 32 + koff;
                        }
                        short8 af = *(const short8*)ap;
                        az = __builtin_amdgcn_mfma_f32_16x16x32_bf16(af, bzc[kt], az, 0, 0, 0);
                        ar = __builtin_amdgcn_mfma_f32_16x16x32_bf16(af, brc[kt], ar, 0, 0, 0);
                    }
                }
            }
#pragma unroll
            for (int i = 0; i < 4; ++i) {
                int e = (quad * 4 + i) * 16 + l15;
                part[v][0][e] = az[i];
                part[v][1][e] = ar[i];
            }
            __syncthreads();
            if (act) {
                const int gate = v >> 1, btf = v & 1;
#pragma unroll
                for (int i = 0; i < 4; ++i) {
                    int e = (quad * 4 + i) * 16 + l15;
                    float sum = part[btf][gate][e] + part[btf + 2][gate][e];
                    int bg_ = btf * 16 + quad * 4 + i;
                    if (gate == 0) {
                        zreg[i] = sigmoidf_(sum + bzv);
                    } else {
                        float r = sigmoidf_(sum + brv);
                        float h = hst[bg_ * H_ + nrow];
                        rh_j[bg_ * H_ + nrow] = f2bf(r * h);
                    }
                }
            }
        } else {
            // ============ output phase 1: out = h2 @ Wout^T + bout ============
            const int t = s - NL_;
            const bool act = (t >= 0);     // t < S_ guaranteed (s <= NSTEP-1)
            floatx4 ao = {0.f, 0.f, 0.f, 0.f};
            if (act) {
                const short* h2 = (const short*)(hbf_base + ((size_t)(2 * 2 + rdpar)) * B_ * H_);
#pragma unroll
                for (int kt = 0; kt < 8; ++kt) {
                    int g = khalf * 8 + kt;
                    short8 af = *(const short8*)(h2 + (long)arow * H_ + g * 32 + koff);
                    ao = __builtin_amdgcn_mfma_f32_16x16x32_bf16(af, wc[kt], ao, 0, 0, 0);
                }
            }
#pragma unroll
            for (int i = 0; i < 4; ++i) {
                int e = (quad * 4 + i) * 16 + l15;
                part[v][0][e] = ao[i];
            }
            __syncthreads();
            if (act && v < 2) {
                const int btf = v;
#pragma unroll
                for (int i = 0; i < 4; ++i) {
                    int e = (quad * 4 + i) * 16 + l15;
                    float sum = part[btf][0][e] + part[btf + 2][0][e];
                    int bg_ = btf * 16 + quad * 4 + i;
                    out[(long)bg_ * (S_ * OUT_) + (long)t * OUT_ + orow] = sum + bov;
                }
            }
        }
        gbar(cnt, gen);

        if (!is_out) {
            // ============ layer phase 2: glin, h update ============
            const int t = s - j;
            const bool act = (t >= 0) && (t < S_);
            floatx4 ag = {0.f, 0.f, 0.f, 0.f};
            if (act) {
                const short* inp_rd = (j == 0) ? nullptr
                                    : (const short*)(hbf_base + ((size_t)((j - 1) * 2 + rdpar)) * B_ * H_);
#pragma unroll
                for (int kt = 0; kt < 16; ++kt) {
                    int g = khalf * 16 + kt;
                    if (g < T1) {
                        const short* ap;
                        if (g < Tx) {
                            if (j == 0) ap = xbf + (long)arow * (S_ * IN_) + (long)t * IN_ + g * 32 + koff;
                            else        ap = inp_rd + (long)arow * H_ + g * 32 + koff;
                        } else {
                            ap = (const short*)rh_j + (long)arow * H_ + (g - Tx) * 32 + koff;
                        }
                        short8 af = *(const short8*)ap;
                        ag = __builtin_amdgcn_mfma_f32_16x16x32_bf16(af, bgc[kt], ag, 0, 0, 0);
                    }
                }
            }
#pragma unroll
            for (int i = 0; i < 4; ++i) {
                int e = (quad * 4 + i) * 16 + l15;
                part[v][0][e] = ag[i];
            }
            __syncthreads();
            if (act && v < 2) {
                const int btf = v;
                unsigned short* hbf_wr = hbf_base + ((size_t)(j * 2 + (s & 1))) * B_ * H_;
#pragma unroll
                for (int i = 0; i < 4; ++i) {
                    int e = (quad * 4 + i) * 16 + l15;
                    float sum = part[btf][0][e] + part[btf + 2][0][e];
                    float gv = tanhf(sum + bgv);
                    int bg_ = btf * 16 + quad * 4 + i;
                    float h = hst[bg_ * H_ + nrow];
                    float z = zreg[i];
                    float hn = z * h + (1.0f - z) * gv;
                    hst[bg_ * H_ + nrow] = hn;
                    hbf_wr[bg_ * H_ + nrow] = f2bf(hn);
                }
            }
        }
        gbar(cnt, gen);
    }
}

// ---------------- post-pass: final hidden state ----------------
__global__ void __launch_bounds__(256) tail_kernel(const char* __restrict__ ws, float* __restrict__ out)
{
    int i = blockIdx.x * 256 + threadIdx.x;
    if (i < B_ * NL_ * H_) {
        int b = i / (NL_ * H_); int r = i % (NL_ * H_); int j = r / H_; int n = r % H_;
        out[B_ * S_ * OUT_ + i] = ((const float*)(ws + OFF_HST))[(j * B_ + b) * H_ + n];
    }
}

extern "C" void kernel_launch(void* const* d_in, const int* in_sizes, int n_in,
                              void* d_out, int out_size, void* d_ws, size_t ws_size,
                              hipStream_t stream)
{
    const float* x   = (const float*)d_in[0];
    const float* h0  = (const float*)d_in[1];
    const float* W0z = (const float*)d_in[2];  const float* b0z = (const float*)d_in[3];
    const float* W0r = (const float*)d_in[4];  const float* b0r = (const float*)d_in[5];
    const float* W0g = (const float*)d_in[6];  const float* b0g = (const float*)d_in[7];
    const float* Wxz = (const float*)d_in[8];  const float* bxz = (const float*)d_in[9];
    const float* Wxr = (const float*)d_in[10]; const float* bxr = (const float*)d_in[11];
    const float* Wxg = (const float*)d_in[12]; const float* bxg = (const float*)d_in[13];
    const float* Whz = (const float*)d_in[14];
    const float* Whr = (const float*)d_in[15];
    const float* Whg = (const float*)d_in[16];
    const float* Wout = (const float*)d_in[17]; const float* bout = (const float*)d_in[18];
    char* ws = (char*)d_ws;
    float* out = (float*)d_out;

    prep_kernel<<<dim3(4096), dim3(1024), 0, stream>>>(
        x, h0, W0z, W0r, W0g, Wxz, Wxr, Wxg, Whz, Whr, Whg, Wout, ws);

    gru_kernel<<<dim3(NWG_TOT), dim3(256), 0, stream>>>(
        ws, b0z, b0r, b0g, bxz, bxr, bxg, bout, out);

    tail_kernel<<<dim3(192), dim3(256), 0, stream>>>((const char*)ws, out);
}

// Round 3
// 30722.598 us; speedup vs baseline: 1.6602x; 1.6602x over previous
//
#include <hip/hip_runtime.h>
#include <cstdint>
#include <cstddef>

// ---------------- problem constants ----------------
#define B_   32
#define S_   1024
#define IN_  128
#define H_   512
#define OUT_ 128
#define NL_  3
#define NWG_LAYER 96            // 3 layers x 32 n-tiles
#define NWG_TOT   104           // + 8 output-projection WGs
#define NSTEP (S_ + NL_)        // 1027 pipeline steps

typedef __attribute__((ext_vector_type(8))) short short8;   // 8 bf16 (4 VGPRs)
typedef __attribute__((ext_vector_type(4))) float floatx4;  // MFMA C/D

// ---------------- workspace layout (bytes); total ~12.6 MB ----------------
constexpr size_t OFF_BAR  = 0;                        // arrive[104] @ 64B stride (8 KB)
constexpr size_t OFF_W0Z  = 8192;                     // 512x128 bf16
constexpr size_t OFF_W0R  = OFF_W0Z + 131072;
constexpr size_t OFF_W0G  = OFF_W0R + 131072;
constexpr size_t OFF_WXZ  = OFF_W0G + 131072;         // 512x512 bf16 each
constexpr size_t OFF_WXR  = OFF_WXZ + 524288;
constexpr size_t OFF_WXG  = OFF_WXR + 524288;
constexpr size_t OFF_WHZ  = OFF_WXG + 524288;
constexpr size_t OFF_WHR  = OFF_WHZ + 524288;
constexpr size_t OFF_WHG  = OFF_WHR + 524288;
constexpr size_t OFF_WOUT = OFF_WHG + 524288;         // 128x512 bf16
constexpr size_t OFF_XBF  = OFF_WOUT + 131072;        // x bf16 [32][1024][128]
constexpr size_t OFF_HST  = OFF_XBF + 8388608;        // f32 h state [3][32][512]
constexpr size_t OFF_HBF  = OFF_HST + 196608;         // bf16 h double-buf [3][2][32][512]
constexpr size_t OFF_RH   = OFF_HBF + 196608;         // bf16 r*h [3][32][512]
// end = OFF_RH + 98304 = ~12.56 MB

__device__ __forceinline__ unsigned short f2bf(float f) {
    unsigned u = __float_as_uint(f);
    unsigned r = (u + 0x7FFFu + ((u >> 16) & 1u)) >> 16;
    return (unsigned short)r;
}
__device__ __forceinline__ float sigmoidf_(float x) { return 1.0f / (1.0f + __expf(-x)); }

// ---------------- pre-pass: converts + init ----------------
__global__ void __launch_bounds__(1024) prep_kernel(
    const float* __restrict__ x, const float* __restrict__ h0,
    const float* __restrict__ W0z, const float* __restrict__ W0r, const float* __restrict__ W0g,
    const float* __restrict__ Wxz, const float* __restrict__ Wxr, const float* __restrict__ Wxg,
    const float* __restrict__ Whz, const float* __restrict__ Whr, const float* __restrict__ Whg,
    const float* __restrict__ Wout, char* __restrict__ ws)
{
    int i = blockIdx.x * 1024 + threadIdx.x;
    unsigned short* xbf = (unsigned short*)(ws + OFF_XBF);
    if (i < B_ * S_ * IN_) xbf[i] = f2bf(x[i]);
    if (i < 65536) {
        ((unsigned short*)(ws + OFF_W0Z))[i]  = f2bf(W0z[i]);
        ((unsigned short*)(ws + OFF_W0R))[i]  = f2bf(W0r[i]);
        ((unsigned short*)(ws + OFF_W0G))[i]  = f2bf(W0g[i]);
        ((unsigned short*)(ws + OFF_WOUT))[i] = f2bf(Wout[i]);
    }
    if (i < 262144) {
        ((unsigned short*)(ws + OFF_WXZ))[i] = f2bf(Wxz[i]);
        ((unsigned short*)(ws + OFF_WXR))[i] = f2bf(Wxr[i]);
        ((unsigned short*)(ws + OFF_WXG))[i] = f2bf(Wxg[i]);
        ((unsigned short*)(ws + OFF_WHZ))[i] = f2bf(Whz[i]);
        ((unsigned short*)(ws + OFF_WHR))[i] = f2bf(Whr[i]);
        ((unsigned short*)(ws + OFF_WHG))[i] = f2bf(Whg[i]);
    }
    if (i < B_ * NL_ * H_) {
        int b = i / (NL_ * H_); int r = i % (NL_ * H_); int j = r / H_; int n = r % H_;
        float v = h0[i];
        ((float*)(ws + OFF_HST))[(j * B_ + b) * H_ + n] = v;
        int par = (j + 1) & 1;  // parity read at layer j's first active step (s=j reads (s-1)&1)
        ((unsigned short*)(ws + OFF_HBF))[((j * 2 + par) * B_ + b) * H_ + n] = f2bf(v);
    }
    if (i < 2048) ((unsigned*)(ws + OFF_BAR))[i] = 0u;   // zero the whole flag region
}

// ---------------- distributed-flag grid barrier (monotonic epoch, master-free) ----------------
// Each WG: one plain device-scope store to its OWN 64B slot (no RMW serialization).
// Every WG polls all NWG_TOT flags itself with RELAXED loads (no per-poll cache inv).
__device__ __forceinline__ void gbar(unsigned* arrive, int wg, unsigned e) {
    __syncthreads();                 // drains vmcnt for all waves -> stores are in L2
    if (threadIdx.x == 0) {
        __threadfence();             // release: wbl2 -> our data visible at LLC
        __hip_atomic_store(arrive + wg * 16, e, __ATOMIC_RELAXED, __HIP_MEMORY_SCOPE_AGENT);
    }
    const int tid = threadIdx.x;
    bool ok;
    do {
        unsigned f = e;
        if (tid < NWG_TOT)
            f = __hip_atomic_load(arrive + tid * 16, __ATOMIC_RELAXED, __HIP_MEMORY_SCOPE_AGENT);
        ok = (f >= e);               // monotonic epochs: >= handles racing-ahead WGs
    } while (!__syncthreads_and(ok));
    __threadfence();                 // acquire: invalidate stale L1/L2 before data reads
}

// ---------------- the scan: 104 WGs, layer+output pipelined, weights in registers ----------------
__global__ void __launch_bounds__(256, 1) gru_kernel(char* ws,
    const float* __restrict__ b0z, const float* __restrict__ b0r, const float* __restrict__ b0g,
    const float* __restrict__ bxz, const float* __restrict__ bxr, const float* __restrict__ bxg,
    const float* __restrict__ bout, float* __restrict__ out)
{
    const int wg    = blockIdx.x;          // 0..103
    const bool is_out = (wg >= NWG_LAYER);
    const int v     = threadIdx.x >> 6;    // wave 0..3
    const int lane  = threadIdx.x & 63;
    const int btile = v & 1;
    const int khalf = v >> 1;
    const int l15   = lane & 15;
    const int quad  = lane >> 4;
    const int koff  = quad * 8;
    const int arow  = btile * 16 + l15;    // A row (batch)

    unsigned short* hbf_base = (unsigned short*)(ws + OFF_HBF);
    unsigned* arrive = (unsigned*)(ws + OFF_BAR);

    __shared__ float part[4][2][256];

    // ----- layer-WG setup -----
    const int j  = is_out ? 0 : (wg >> 5);     // layer 0..2
    const int nt = wg & 31;                    // n-tile
    const int nrow = nt * 16 + l15;            // feature (layer path)
    const int Tx = (j == 0) ? 4 : 16;          // x-part k-tiles (32 elems each)
    const int T1 = Tx + 16;                    // + h-part
    float bzv = 0.f, brv = 0.f, bgv = 0.f;
    short8 bzc[16], brc[16], bgc[16];
    const short* xbf = (const short*)(ws + OFF_XBF);
    float* hst = (float*)(ws + OFF_HST) + (size_t)j * B_ * H_;
    unsigned short* rh_j = (unsigned short*)(ws + OFF_RH) + (size_t)j * B_ * H_;

    // ----- output-WG setup -----
    const int ont  = wg - NWG_LAYER;           // 0..7
    const int orow = ont * 16 + l15;           // out feature 0..127
    short8 wc[8];
    float bov = 0.f;

    if (!is_out) {
        const float* bz_b = (j == 0) ? b0z : bxz;
        const float* br_b = (j == 0) ? b0r : bxr;
        const float* bg_b = (j == 0) ? b0g : bxg;
        bzv = bz_b[nrow]; brv = br_b[nrow]; bgv = bg_b[nrow];
        const int strx = (j == 0) ? IN_ : H_;
        const short* Wz_x = (const short*)(ws + ((j == 0) ? OFF_W0Z : OFF_WXZ));
        const short* Wr_x = (const short*)(ws + ((j == 0) ? OFF_W0R : OFF_WXR));
        const short* Wg_x = (const short*)(ws + ((j == 0) ? OFF_W0G : OFF_WXG));
        const short* Wz_h = (const short*)(ws + OFF_WHZ);
        const short* Wr_h = (const short*)(ws + OFF_WHR);
        const short* Wg_h = (const short*)(ws + OFF_WHG);
#pragma unroll
        for (int kt = 0; kt < 16; ++kt) {
            short8 z8 = {0, 0, 0, 0, 0, 0, 0, 0};
            bzc[kt] = z8; brc[kt] = z8; bgc[kt] = z8;
            int g = khalf * 16 + kt;
            if (g < T1) {
                if (g < Tx) {
                    long o = (long)nrow * strx + g * 32 + koff;
                    bzc[kt] = *(const short8*)(Wz_x + o);
                    brc[kt] = *(const short8*)(Wr_x + o);
                    bgc[kt] = *(const short8*)(Wg_x + o);
                } else {
                    long o = (long)nrow * H_ + (g - Tx) * 32 + koff;
                    bzc[kt] = *(const short8*)(Wz_h + o);
                    brc[kt] = *(const short8*)(Wr_h + o);
                    bgc[kt] = *(const short8*)(Wg_h + o);
                }
            }
        }
    } else {
        const short* Wo = (const short*)(ws + OFF_WOUT);
        bov = bout[orow];
#pragma unroll
        for (int kt = 0; kt < 8; ++kt) {
            int g = khalf * 8 + kt;   // 16 k-tiles total, split 8/8 across khalf
            wc[kt] = *(const short8*)(Wo + (long)orow * H_ + g * 32 + koff);
        }
    }

    float zreg[4] = {0.f, 0.f, 0.f, 0.f};

#pragma unroll 1
    for (int s = 0; s < NSTEP; ++s) {
        const int rdpar = (s - 1) & 1;
        const unsigned e1 = 2u * s + 1u, e2 = 2u * s + 2u;

        if (!is_out) {
            // ============ layer phase 1: zlin, rlin ============
            const int t = s - j;
            const bool act = (t >= 0) && (t < S_);
            floatx4 az = {0.f, 0.f, 0.f, 0.f}, ar = {0.f, 0.f, 0.f, 0.f};
            if (act) {
                const short* hbf_rd = (const short*)(hbf_base + ((size_t)(j * 2 + rdpar)) * B_ * H_);
                const short* inp_rd = (j == 0) ? nullptr
                                    : (const short*)(hbf_base + ((size_t)((j - 1) * 2 + rdpar)) * B_ * H_);
#pragma unroll
                for (int kt = 0; kt < 16; ++kt) {
                    int g = khalf * 16 + kt;
                    if (g < T1) {
                        const short* ap;
                        if (g < Tx) {
                            if (j == 0) ap = xbf + (long)arow * (S_ * IN_) + (long)t * IN_ + g * 32 + koff;
                            else        ap = inp_rd + (long)arow * H_ + g * 32 + koff;
                        } else {
                            ap = hbf_rd + (long)arow * H_ + (g - Tx) * 32 + koff;
                        }
                        short8 af = *(const short8*)ap;
                        az = __builtin_amdgcn_mfma_f32_16x16x32_bf16(af, bzc[kt], az, 0, 0, 0);
                        ar = __builtin_amdgcn_mfma_f32_16x16x32_bf16(af, brc[kt], ar, 0, 0, 0);
                    }
                }
            }
#pragma unroll
            for (int i = 0; i < 4; ++i) {
                int e = (quad * 4 + i) * 16 + l15;
                part[v][0][e] = az[i];
                part[v][1][e] = ar[i];
            }
            __syncthreads();
            if (act) {
                const int gate = v >> 1, btf = v & 1;
#pragma unroll
                for (int i = 0; i < 4; ++i) {
                    int e = (quad * 4 + i) * 16 + l15;
                    float sum = part[btf][gate][e] + part[btf + 2][gate][e];
                    int bg_ = btf * 16 + quad * 4 + i;
                    if (gate == 0) {
                        zreg[i] = sigmoidf_(sum + bzv);
                    } else {
                        float r = sigmoidf_(sum + brv);
                        float h = hst[bg_ * H_ + nrow];
                        rh_j[bg_ * H_ + nrow] = f2bf(r * h);
                    }
                }
            }
        } else {
            // ============ output phase 1: out = h2 @ Wout^T + bout ============
            const int t = s - NL_;
            const bool act = (t >= 0);     // t < S_ guaranteed (s <= NSTEP-1)
            floatx4 ao = {0.f, 0.f, 0.f, 0.f};
            if (act) {
                const short* h2 = (const short*)(hbf_base + ((size_t)(2 * 2 + rdpar)) * B_ * H_);
#pragma unroll
                for (int kt = 0; kt < 8; ++kt) {
                    int g = khalf * 8 + kt;
                    short8 af = *(const short8*)(h2 + (long)arow * H_ + g * 32 + koff);
                    ao = __builtin_amdgcn_mfma_f32_16x16x32_bf16(af, wc[kt], ao, 0, 0, 0);
                }
            }
#pragma unroll
            for (int i = 0; i < 4; ++i) {
                int e = (quad * 4 + i) * 16 + l15;
                part[v][0][e] = ao[i];
            }
            __syncthreads();
            if (act && v < 2) {
                const int btf = v;
#pragma unroll
                for (int i = 0; i < 4; ++i) {
                    int e = (quad * 4 + i) * 16 + l15;
                    float sum = part[btf][0][e] + part[btf + 2][0][e];
                    int bg_ = btf * 16 + quad * 4 + i;
                    out[(long)bg_ * (S_ * OUT_) + (long)t * OUT_ + orow] = sum + bov;
                }
            }
        }
        gbar(arrive, wg, e1);

        if (!is_out) {
            // ============ layer phase 2: glin, h update ============
            const int t = s - j;
            const bool act = (t >= 0) && (t < S_);
            floatx4 ag = {0.f, 0.f, 0.f, 0.f};
            if (act) {
                const short* inp_rd = (j == 0) ? nullptr
                                    : (const short*)(hbf_base + ((size_t)((j - 1) * 2 + rdpar)) * B_ * H_);
#pragma unroll
                for (int kt = 0; kt < 16; ++kt) {
                    int g = khalf * 16 + kt;
                    if (g < T1) {
                        const short* ap;
                        if (g < Tx) {
                            if (j == 0) ap = xbf + (long)arow * (S_ * IN_) + (long)t * IN_ + g * 32 + koff;
                            else        ap = inp_rd + (long)arow * H_ + g * 32 + koff;
                        } else {
                            ap = (const short*)rh_j + (long)arow * H_ + (g - Tx) * 32 + koff;
                        }
                        short8 af = *(const short8*)ap;
                        ag = __builtin_amdgcn_mfma_f32_16x16x32_bf16(af, bgc[kt], ag, 0, 0, 0);
                    }
                }
            }
#pragma unroll
            for (int i = 0; i < 4; ++i) {
                int e = (quad * 4 + i) * 16 + l15;
                part[v][0][e] = ag[i];
            }
            __syncthreads();
            if (act && v < 2) {
                const int btf = v;
                unsigned short* hbf_wr = hbf_base + ((size_t)(j * 2 + (s & 1))) * B_ * H_;
#pragma unroll
                for (int i = 0; i < 4; ++i) {
                    int e = (quad * 4 + i) * 16 + l15;
                    float sum = part[btf][0][e] + part[btf + 2][0][e];
                    float gv = tanhf(sum + bgv);
                    int bg_ = btf * 16 + quad * 4 + i;
                    float h = hst[bg_ * H_ + nrow];
                    float z = zreg[i];
                    float hn = z * h + (1.0f - z) * gv;
                    hst[bg_ * H_ + nrow] = hn;
                    hbf_wr[bg_ * H_ + nrow] = f2bf(hn);
                }
            }
        }
        gbar(arrive, wg, e2);
    }
}

// ---------------- post-pass: final hidden state ----------------
__global__ void __launch_bounds__(256) tail_kernel(const char* __restrict__ ws, float* __restrict__ out)
{
    int i = blockIdx.x * 256 + threadIdx.x;
    if (i < B_ * NL_ * H_) {
        int b = i / (NL_ * H_); int r = i % (NL_ * H_); int j = r / H_; int n = r % H_;
        out[B_ * S_ * OUT_ + i] = ((const float*)(ws + OFF_HST))[(j * B_ + b) * H_ + n];
    }
}

extern "C" void kernel_launch(void* const* d_in, const int* in_sizes, int n_in,
                              void* d_out, int out_size, void* d_ws, size_t ws_size,
                              hipStream_t stream)
{
    const float* x   = (const float*)d_in[0];
    const float* h0  = (const float*)d_in[1];
    const float* W0z = (const float*)d_in[2];  const float* b0z = (const float*)d_in[3];
    const float* W0r = (const float*)d_in[4];  const float* b0r = (const float*)d_in[5];
    const float* W0g = (const float*)d_in[6];  const float* b0g = (const float*)d_in[7];
    const float* Wxz = (const float*)d_in[8];  const float* bxz = (const float*)d_in[9];
    const float* Wxr = (const float*)d_in[10]; const float* bxr = (const float*)d_in[11];
    const float* Wxg = (const float*)d_in[12]; const float* bxg = (const float*)d_in[13];
    const float* Whz = (const float*)d_in[14];
    const float* Whr = (const float*)d_in[15];
    const float* Whg = (const float*)d_in[16];
    const float* Wout = (const float*)d_in[17]; const float* bout = (const float*)d_in[18];
    char* ws = (char*)d_ws;
    float* out = (float*)d_out;

    prep_kernel<<<dim3(4096), dim3(1024), 0, stream>>>(
        x, h0, W0z, W0r, W0g, Wxz, Wxr, Wxg, Whz, Whr, Whg, Wout, ws);

    gru_kernel<<<dim3(NWG_TOT), dim3(256), 0, stream>>>(
        ws, b0z, b0r, b0g, bxz, bxr, bxg, bout, out);

    tail_kernel<<<dim3(192), dim3(256), 0, stream>>>((const char*)ws, out);
}

// Round 4
// 17164.441 us; speedup vs baseline: 2.9715x; 1.7899x over previous
//
#include <hip/hip_runtime.h>
#include <cstdint>
#include <cstddef>

// ---------------- problem constants ----------------
#define B_   32
#define S_   1024
#define IN_  128
#define H_   512
#define OUT_ 128
#define NL_  3
#define NWG_LAYER 96            // 3 layers x 32 n-tiles
#define NWG_TOT   104           // + 8 output-projection WGs
#define NSTEP (S_ + NL_)        // 1027 pipeline steps

typedef __attribute__((ext_vector_type(8))) short short8;   // 8 bf16 (4 VGPRs)
typedef __attribute__((ext_vector_type(4))) float floatx4;  // MFMA C/D

// ---------------- workspace layout (bytes); total ~12.6 MB ----------------
constexpr size_t OFF_BAR  = 0;                        // arrive[104] @ 64B stride (8 KB)
constexpr size_t OFF_W0Z  = 8192;                     // 512x128 bf16
constexpr size_t OFF_W0R  = OFF_W0Z + 131072;
constexpr size_t OFF_W0G  = OFF_W0R + 131072;
constexpr size_t OFF_WXZ  = OFF_W0G + 131072;         // 512x512 bf16 each
constexpr size_t OFF_WXR  = OFF_WXZ + 524288;
constexpr size_t OFF_WXG  = OFF_WXR + 524288;
constexpr size_t OFF_WHZ  = OFF_WXG + 524288;
constexpr size_t OFF_WHR  = OFF_WHZ + 524288;
constexpr size_t OFF_WHG  = OFF_WHR + 524288;
constexpr size_t OFF_WOUT = OFF_WHG + 524288;         // 128x512 bf16
constexpr size_t OFF_XBF  = OFF_WOUT + 131072;        // x bf16 [32][1024][128]
constexpr size_t OFF_HST  = OFF_XBF + 8388608;        // f32 h state [3][32][512] (WG-private strips)
constexpr size_t OFF_HBF  = OFF_HST + 196608;         // bf16 h double-buf [3][2][32][512] (cross-WG, sc1)
constexpr size_t OFF_RH   = OFF_HBF + 196608;         // bf16 r*h [3][32][512] (cross-WG, sc1)
// end = OFF_RH + 98304 = ~12.56 MB

__device__ __forceinline__ unsigned short f2bf(float f) {
    unsigned u = __float_as_uint(f);
    unsigned r = (u + 0x7FFFu + ((u >> 16) & 1u)) >> 16;
    return (unsigned short)r;
}
__device__ __forceinline__ float sigmoidf_(float x) { return 1.0f / (1.0f + __expf(-x)); }

// ---- coherent (LLC-level) access helpers: no fences needed anywhere ----
// 16B cross-WG read as 2x8B relaxed agent atomics -> global_load_dwordx2 sc0 sc1
__device__ __forceinline__ short8 load16_coh(const void* p) {
    union { unsigned long long u[2]; short8 s; } r;
    const unsigned long long* q = (const unsigned long long*)p;
    r.u[0] = __hip_atomic_load(q,     __ATOMIC_RELAXED, __HIP_MEMORY_SCOPE_AGENT);
    r.u[1] = __hip_atomic_load(q + 1, __ATOMIC_RELAXED, __HIP_MEMORY_SCOPE_AGENT);
    return r.s;
}
// 2B cross-WG write-through to LLC (byte-granular merge at LLC)
__device__ __forceinline__ void store2_coh(void* p, unsigned short v_) {
    unsigned v32 = v_;
    asm volatile("global_store_short %0, %1, off sc0 sc1" :: "v"(p), "v"(v32) : "memory");
}

// ---------------- pre-pass: converts + init ----------------
__global__ void __launch_bounds__(1024) prep_kernel(
    const float* __restrict__ x, const float* __restrict__ h0,
    const float* __restrict__ W0z, const float* __restrict__ W0r, const float* __restrict__ W0g,
    const float* __restrict__ Wxz, const float* __restrict__ Wxr, const float* __restrict__ Wxg,
    const float* __restrict__ Whz, const float* __restrict__ Whr, const float* __restrict__ Whg,
    const float* __restrict__ Wout, char* __restrict__ ws)
{
    int i = blockIdx.x * 1024 + threadIdx.x;
    unsigned short* xbf = (unsigned short*)(ws + OFF_XBF);
    if (i < B_ * S_ * IN_) xbf[i] = f2bf(x[i]);
    if (i < 65536) {
        ((unsigned short*)(ws + OFF_W0Z))[i]  = f2bf(W0z[i]);
        ((unsigned short*)(ws + OFF_W0R))[i]  = f2bf(W0r[i]);
        ((unsigned short*)(ws + OFF_W0G))[i]  = f2bf(W0g[i]);
        ((unsigned short*)(ws + OFF_WOUT))[i] = f2bf(Wout[i]);
    }
    if (i < 262144) {
        ((unsigned short*)(ws + OFF_WXZ))[i] = f2bf(Wxz[i]);
        ((unsigned short*)(ws + OFF_WXR))[i] = f2bf(Wxr[i]);
        ((unsigned short*)(ws + OFF_WXG))[i] = f2bf(Wxg[i]);
        ((unsigned short*)(ws + OFF_WHZ))[i] = f2bf(Whz[i]);
        ((unsigned short*)(ws + OFF_WHR))[i] = f2bf(Whr[i]);
        ((unsigned short*)(ws + OFF_WHG))[i] = f2bf(Whg[i]);
    }
    if (i < B_ * NL_ * H_) {
        int b = i / (NL_ * H_); int r = i % (NL_ * H_); int j = r / H_; int n = r % H_;
        float v = h0[i];
        ((float*)(ws + OFF_HST))[(j * B_ + b) * H_ + n] = v;
        int par = (j + 1) & 1;  // parity read at layer j's first active step (s=j reads (s-1)&1)
        ((unsigned short*)(ws + OFF_HBF))[((j * 2 + par) * B_ + b) * H_ + n] = f2bf(v);
    }
    if (i < 2048) ((unsigned*)(ws + OFF_BAR))[i] = 0u;   // zero the whole flag region
}

// ---------------- fence-free distributed-flag grid barrier ----------------
// All cross-WG data moves via sc0sc1 (LLC write-through / LLC-bypass loads), so
// visibility needs only: per-wave s_waitcnt vmcnt(0)  ->  flag store  ->  poll.
__device__ __forceinline__ void gbar(unsigned* arrive, int wg, unsigned e) {
    asm volatile("s_waitcnt vmcnt(0)" ::: "memory");  // every wave: its sc1 stores are at LLC
    __syncthreads();                                  // whole WG drained
    if (threadIdx.x == 0)
        __hip_atomic_store(arrive + wg * 16, e, __ATOMIC_RELAXED, __HIP_MEMORY_SCOPE_AGENT);
    const int tid = threadIdx.x;
    bool ok;
    do {
        unsigned f = e;
        if (tid < NWG_TOT)
            f = __hip_atomic_load(arrive + tid * 16, __ATOMIC_RELAXED, __HIP_MEMORY_SCOPE_AGENT);
        ok = (f >= e);               // monotonic epochs: >= handles racing-ahead WGs
    } while (!__syncthreads_and(ok));
    // no acquire fence: subsequent cross-WG loads are sc1 (LLC-fresh), issued in
    // program order after the poll observed the flag.
}

// ---------------- the scan: 104 WGs, layer+output pipelined, weights in registers ----------------
__global__ void __launch_bounds__(256, 1) gru_kernel(char* ws,
    const float* __restrict__ b0z, const float* __restrict__ b0r, const float* __restrict__ b0g,
    const float* __restrict__ bxz, const float* __restrict__ bxr, const float* __restrict__ bxg,
    const float* __restrict__ bout, float* __restrict__ out)
{
    const int wg    = blockIdx.x;          // 0..103
    const bool is_out = (wg >= NWG_LAYER);
    const int v     = threadIdx.x >> 6;    // wave 0..3
    const int lane  = threadIdx.x & 63;
    const int btile = v & 1;
    const int khalf = v >> 1;
    const int l15   = lane & 15;
    const int quad  = lane >> 4;
    const int koff  = quad * 8;
    const int arow  = btile * 16 + l15;    // A row (batch)

    unsigned short* hbf_base = (unsigned short*)(ws + OFF_HBF);
    unsigned* arrive = (unsigned*)(ws + OFF_BAR);

    __shared__ float part[4][2][256];

    // ----- layer-WG setup -----
    const int j  = is_out ? 0 : (wg >> 5);     // layer 0..2
    const int nt = wg & 31;                    // n-tile
    const int nrow = nt * 16 + l15;            // feature (layer path)
    const int Tx = (j == 0) ? 4 : 16;          // x-part k-tiles (32 elems each)
    const int T1 = Tx + 16;                    // + h-part
    float bzv = 0.f, brv = 0.f, bgv = 0.f;
    short8 bzc[16], brc[16], bgc[16];
    const short* xbf = (const short*)(ws + OFF_XBF);
    float* hst = (float*)(ws + OFF_HST) + (size_t)j * B_ * H_;
    unsigned short* rh_j = (unsigned short*)(ws + OFF_RH) + (size_t)j * B_ * H_;

    // ----- output-WG setup -----
    const int ont  = wg - NWG_LAYER;           // 0..7
    const int orow = ont * 16 + l15;           // out feature 0..127
    short8 wc[8];
    float bov = 0.f;

    if (!is_out) {
        const float* bz_b = (j == 0) ? b0z : bxz;
        const float* br_b = (j == 0) ? b0r : bxr;
        const float* bg_b = (j == 0) ? b0g : bxg;
        bzv = bz_b[nrow]; brv = br_b[nrow]; bgv = bg_b[nrow];
        const int strx = (j == 0) ? IN_ : H_;
        const short* Wz_x = (const short*)(ws + ((j == 0) ? OFF_W0Z : OFF_WXZ));
        const short* Wr_x = (const short*)(ws + ((j == 0) ? OFF_W0R : OFF_WXR));
        const short* Wg_x = (const short*)(ws + ((j == 0) ? OFF_W0G : OFF_WXG));
        const short* Wz_h = (const short*)(ws + OFF_WHZ);
        const short* Wr_h = (const short*)(ws + OFF_WHR);
        const short* Wg_h = (const short*)(ws + OFF_WHG);
#pragma unroll
        for (int kt = 0; kt < 16; ++kt) {
            short8 z8 = {0, 0, 0, 0, 0, 0, 0, 0};
            bzc[kt] = z8; brc[kt] = z8; bgc[kt] = z8;
            int g = khalf * 16 + kt;
            if (g < T1) {
                if (g < Tx) {
                    long o = (long)nrow * strx + g * 32 + koff;
                    bzc[kt] = *(const short8*)(Wz_x + o);
                    brc[kt] = *(const short8*)(Wr_x + o);
                    bgc[kt] = *(const short8*)(Wg_x + o);
                } else {
                    long o = (long)nrow * H_ + (g - Tx) * 32 + koff;
                    bzc[kt] = *(const short8*)(Wz_h + o);
                    brc[kt] = *(const short8*)(Wr_h + o);
                    bgc[kt] = *(const short8*)(Wg_h + o);
                }
            }
        }
    } else {
        const short* Wo = (const short*)(ws + OFF_WOUT);
        bov = bout[orow];
#pragma unroll
        for (int kt = 0; kt < 8; ++kt) {
            int g = khalf * 8 + kt;   // 16 k-tiles total, split 8/8 across khalf
            wc[kt] = *(const short8*)(Wo + (long)orow * H_ + g * 32 + koff);
        }
    }

    float zreg[4] = {0.f, 0.f, 0.f, 0.f};

#pragma unroll 1
    for (int s = 0; s < NSTEP; ++s) {
        const int rdpar = (s - 1) & 1;
        const unsigned e1 = 2u * s + 1u, e2 = 2u * s + 2u;

        if (!is_out) {
            // ============ layer phase 1: zlin, rlin ============
            const int t = s - j;
            const bool act = (t >= 0) && (t < S_);
            floatx4 az = {0.f, 0.f, 0.f, 0.f}, ar = {0.f, 0.f, 0.f, 0.f};
            if (act) {
                const short* hbf_rd = (const short*)(hbf_base + ((size_t)(j * 2 + rdpar)) * B_ * H_);
                const short* inp_rd = (j == 0) ? nullptr
                                    : (const short*)(hbf_base + ((size_t)((j - 1) * 2 + rdpar)) * B_ * H_);
#pragma unroll
                for (int kt = 0; kt < 16; ++kt) {
                    int g = khalf * 16 + kt;
                    if (g < T1) {
                        short8 af;
                        if (g < Tx) {
                            if (j == 0) af = *(const short8*)(xbf + (long)arow * (S_ * IN_) + (long)t * IN_ + g * 32 + koff);
                            else        af = load16_coh(inp_rd + (long)arow * H_ + g * 32 + koff);
                        } else {
                            af = load16_coh(hbf_rd + (long)arow * H_ + (g - Tx) * 32 + koff);
                        }
                        az = __builtin_amdgcn_mfma_f32_16x16x32_bf16(af, bzc[kt], az, 0, 0, 0);
                        ar = __builtin_amdgcn_mfma_f32_16x16x32_bf16(af, brc[kt], ar, 0, 0, 0);
                    }
                }
            }
#pragma unroll
            for (int i = 0; i < 4; ++i) {
                int e = (quad * 4 + i) * 16 + l15;
                part[v][0][e] = az[i];
                part[v][1][e] = ar[i];
            }
            __syncthreads();
            if (act) {
                const int gate = v >> 1, btf = v & 1;
#pragma unroll
                for (int i = 0; i < 4; ++i) {
                    int e = (quad * 4 + i) * 16 + l15;
                    float sum = part[btf][gate][e] + part[btf + 2][gate][e];
                    int bg_ = btf * 16 + quad * 4 + i;
                    if (gate == 0) {
                        zreg[i] = sigmoidf_(sum + bzv);
                    } else {
                        float r = sigmoidf_(sum + brv);
                        float h = hst[bg_ * H_ + nrow];
                        store2_coh(rh_j + bg_ * H_ + nrow, f2bf(r * h));
                    }
                }
            }
        } else {
            // ============ output phase 1: out = h2 @ Wout^T + bout ============
            const int t = s - NL_;
            const bool act = (t >= 0);     // t < S_ guaranteed (s <= NSTEP-1)
            floatx4 ao = {0.f, 0.f, 0.f, 0.f};
            if (act) {
                const short* h2 = (const short*)(hbf_base + ((size_t)(2 * 2 + rdpar)) * B_ * H_);
#pragma unroll
                for (int kt = 0; kt < 8; ++kt) {
                    int g = khalf * 8 + kt;
                    short8 af = load16_coh(h2 + (long)arow * H_ + g * 32 + koff);
                    ao = __builtin_amdgcn_mfma_f32_16x16x32_bf16(af, wc[kt], ao, 0, 0, 0);
                }
            }
#pragma unroll
            for (int i = 0; i < 4; ++i) {
                int e = (quad * 4 + i) * 16 + l15;
                part[v][0][e] = ao[i];
            }
            __syncthreads();
            if (act && v < 2) {
                const int btf = v;
#pragma unroll
                for (int i = 0; i < 4; ++i) {
                    int e = (quad * 4 + i) * 16 + l15;
                    float sum = part[btf][0][e] + part[btf + 2][0][e];
                    int bg_ = btf * 16 + quad * 4 + i;
                    out[(long)bg_ * (S_ * OUT_) + (long)t * OUT_ + orow] = sum + bov;
                }
            }
        }
        gbar(arrive, wg, e1);

        if (!is_out) {
            // ============ layer phase 2: glin, h update ============
            const int t = s - j;
            const bool act = (t >= 0) && (t < S_);
            floatx4 ag = {0.f, 0.f, 0.f, 0.f};
            if (act) {
                const short* inp_rd = (j == 0) ? nullptr
                                    : (const short*)(hbf_base + ((size_t)((j - 1) * 2 + rdpar)) * B_ * H_);
#pragma unroll
                for (int kt = 0; kt < 16; ++kt) {
                    int g = khalf * 16 + kt;
                    if (g < T1) {
                        short8 af;
                        if (g < Tx) {
                            if (j == 0) af = *(const short8*)(xbf + (long)arow * (S_ * IN_) + (long)t * IN_ + g * 32 + koff);
                            else        af = load16_coh(inp_rd + (long)arow * H_ + g * 32 + koff);
                        } else {
                            af = load16_coh((const short*)rh_j + (long)arow * H_ + (g - Tx) * 32 + koff);
                        }
                        ag = __builtin_amdgcn_mfma_f32_16x16x32_bf16(af, bgc[kt], ag, 0, 0, 0);
                    }
                }
            }
#pragma unroll
            for (int i = 0; i < 4; ++i) {
                int e = (quad * 4 + i) * 16 + l15;
                part[v][0][e] = ag[i];
            }
            __syncthreads();
            if (act && v < 2) {
                const int btf = v;
                unsigned short* hbf_wr = hbf_base + ((size_t)(j * 2 + (s & 1))) * B_ * H_;
#pragma unroll
                for (int i = 0; i < 4; ++i) {
                    int e = (quad * 4 + i) * 16 + l15;
                    float sum = part[btf][0][e] + part[btf + 2][0][e];
                    float gv = tanhf(sum + bgv);
                    int bg_ = btf * 16 + quad * 4 + i;
                    float h = hst[bg_ * H_ + nrow];
                    float z = zreg[i];
                    float hn = z * h + (1.0f - z) * gv;
                    hst[bg_ * H_ + nrow] = hn;
                    store2_coh(hbf_wr + bg_ * H_ + nrow, f2bf(hn));
                }
            }
        }
        gbar(arrive, wg, e2);
    }
}

// ---------------- post-pass: final hidden state ----------------
__global__ void __launch_bounds__(256) tail_kernel(const char* __restrict__ ws, float* __restrict__ out)
{
    int i = blockIdx.x * 256 + threadIdx.x;
    if (i < B_ * NL_ * H_) {
        int b = i / (NL_ * H_); int r = i % (NL_ * H_); int j = r / H_; int n = r % H_;
        out[B_ * S_ * OUT_ + i] = ((const float*)(ws + OFF_HST))[(j * B_ + b) * H_ + n];
    }
}

extern "C" void kernel_launch(void* const* d_in, const int* in_sizes, int n_in,
                              void* d_out, int out_size, void* d_ws, size_t ws_size,
                              hipStream_t stream)
{
    const float* x   = (const float*)d_in[0];
    const float* h0  = (const float*)d_in[1];
    const float* W0z = (const float*)d_in[2];  const float* b0z = (const float*)d_in[3];
    const float* W0r = (const float*)d_in[4];  const float* b0r = (const float*)d_in[5];
    const float* W0g = (const float*)d_in[6];  const float* b0g = (const float*)d_in[7];
    const float* Wxz = (const float*)d_in[8];  const float* bxz = (const float*)d_in[9];
    const float* Wxr = (const float*)d_in[10]; const float* bxr = (const float*)d_in[11];
    const float* Wxg = (const float*)d_in[12]; const float* bxg = (const float*)d_in[13];
    const float* Whz = (const float*)d_in[14];
    const float* Whr = (const float*)d_in[15];
    const float* Whg = (const float*)d_in[16];
    const float* Wout = (const float*)d_in[17]; const float* bout = (const float*)d_in[18];
    char* ws = (char*)d_ws;
    float* out = (float*)d_out;

    prep_kernel<<<dim3(4096), dim3(1024), 0, stream>>>(
        x, h0, W0z, W0r, W0g, Wxz, Wxr, Wxg, Whz, Whr, Whg, Wout, ws);

    gru_kernel<<<dim3(NWG_TOT), dim3(256), 0, stream>>>(
        ws, b0z, b0r, b0g, bxz, bxr, bxg, bout, out);

    tail_kernel<<<dim3(192), dim3(256), 0, stream>>>((const char*)ws, out);
}